// Round 9
// baseline (1355.213 us; speedup 1.0000x reference)
//
#include <hip/hip_runtime.h>
#include <hip/hip_fp16.h>
#include <math.h>

// GCN 2-layer. norm_e = dinv[src]*dinv[dst] factorizes: pre-scale at source
// (gemm1 epilogue), aggregate raw, post-scale at destination.
// R8 insight: ANY multi-CU scatter of 4B entries write-amplifies ~13x because
// adjacent entries of a 64B line land in different non-coherent XCD L2s.
// So: no sorted CSR at all. k_part buckets edges into 49 regions of packed
// (src<<11|dstloc) pairs with LDS-FIFO chunked writes (amp~1, proven R7);
// aggregation streams pairs per 256-node sub-bucket into LDS accumulators
// (ds_add_f32), fusing self-loop, dinv, bias, relu, W2 (layer1) and
// log_softmax (layer2). Deletes bucketfill/rowptr-scans/colidx entirely.

constexpr int N    = 100000;
constexpr int E    = 3200000;
constexpr int F_IN = 128;
constexpr int H    = 50;
constexpr int C    = 2;
constexpr int HP   = 64;                  // padded h1 row (halves), 128 B

constexpr int BSH   = 11;                 // 2048 nodes per coarse bucket
constexpr int BSZ   = 1 << BSH;
constexpr int NBUCK = (N + BSZ - 1) / BSZ;        // 49
constexpr int PART_NBLK = 256;
constexpr int EPB   = E / PART_NBLK;      // 12500
constexpr int CAP   = 48;                 // FIFO capacity per bucket

constexpr int XS_LD = F_IN + 4;
constexpr int WS_LD = 64;
constexpr int ACC_LD = 52;                // acc row pad (bank spread)

typedef int int4v __attribute__((ext_vector_type(4)));
typedef short short8v __attribute__((ext_vector_type(8)));

__device__ inline float h2f(short s) {
    unsigned short us = (unsigned short)s;
    __half h;
    __builtin_memcpy(&h, &us, 2);
    return __half2float(h);
}

// ---------------- CSR-free build ----------------

__global__ __launch_bounds__(256) void k_zero(int* __restrict__ degi,
                                              int* __restrict__ bcnt) {
    int i = blockIdx.x * blockDim.x + threadIdx.x;
    if (i < N) degi[i] = 0;
    if (i < NBUCK) bcnt[i] = 0;
}

__global__ __launch_bounds__(256) void k_coarse(const int* __restrict__ dst,
                                                int* __restrict__ bcnt) {
    __shared__ int h[NBUCK];
    const int t = threadIdx.x;
    if (t < NBUCK) h[t] = 0;
    __syncthreads();
    const int4v* dst4 = (const int4v*)dst;
    long q0 = (long)blockIdx.x * (EPB / 4), q1 = q0 + EPB / 4;
    for (long q = q0 + t; q < q1; q += 256) {
        int4v d = __builtin_nontemporal_load(dst4 + q);
        atomicAdd(&h[d.x >> BSH], 1);
        atomicAdd(&h[d.y >> BSH], 1);
        atomicAdd(&h[d.z >> BSH], 1);
        atomicAdd(&h[d.w >> BSH], 1);
    }
    __syncthreads();
    if (t < NBUCK) atomicAdd(&bcnt[t], h[t]);
}

__global__ __launch_bounds__(64) void k_scan49(const int* __restrict__ bcnt,
                                               int* __restrict__ bptr,
                                               int* __restrict__ gcur) {
    if (threadIdx.x == 0) {
        int run = 0;
        for (int k = 0; k < NBUCK; ++k) {
            bptr[k] = run; gcur[k] = run; run += bcnt[k];
        }
        bptr[NBUCK] = run;   // == E
    }
}

// scatter packed pairs into bucket regions; LDS FIFO -> contiguous chunks
__global__ __launch_bounds__(256) void k_part(const int* __restrict__ src,
                                              const int* __restrict__ dst,
                                              int* __restrict__ gcur,
                                              int* __restrict__ pairs) {
    __shared__ int fifo[NBUCK][CAP];
    __shared__ int lcnt[NBUCK];
    const int t = threadIdx.x;
    if (t < NBUCK) lcnt[t] = 0;
    __syncthreads();
    const int4v* dst4 = (const int4v*)dst;
    const int4v* src4 = (const int4v*)src;
    long q0 = (long)blockIdx.x * (EPB / 4), qend = q0 + EPB / 4;
    for (long qb = q0; qb < qend; qb += 256) {
        long q = qb + t;
        if (q < qend) {
            int4v d = __builtin_nontemporal_load(dst4 + q);
            int4v s = __builtin_nontemporal_load(src4 + q);
            #pragma unroll
            for (int u = 0; u < 4; ++u) {
                int dd = (u == 0) ? d.x : (u == 1) ? d.y : (u == 2) ? d.z : d.w;
                int ss = (u == 0) ? s.x : (u == 1) ? s.y : (u == 2) ? s.z : s.w;
                int b  = dd >> BSH;
                int pk = (ss << BSH) | (dd & (BSZ - 1));
                int pos = atomicAdd(&lcnt[b], 1);
                if (pos < CAP) fifo[b][pos] = pk;
                else { int p = atomicAdd(&gcur[b], 1); pairs[p] = pk; }
            }
        }
        __syncthreads();
        if (t < NBUCK) {
            int c = lcnt[t]; if (c > CAP) c = CAP;
            if (c > 0) {
                int base = atomicAdd(&gcur[t], c);
                for (int j = 0; j < c; ++j) pairs[base + j] = fifo[t][j];
                lcnt[t] = 0;
            }
        }
        __syncthreads();
    }
}

// per-bucket degree histogram -> degi (edge degree, self-loop excluded)
__global__ __launch_bounds__(256) void k_bdeg(const int* __restrict__ pairs,
                                              const int* __restrict__ bptr,
                                              int* __restrict__ degi) {
    __shared__ int cnt[BSZ];
    const int t = threadIdx.x;
    const int k = blockIdx.x >> 3, j = blockIdx.x & 7;
    for (int i = t; i < BSZ; i += 256) cnt[i] = 0;
    __syncthreads();
    int p0 = bptr[k], len = bptr[k + 1] - p0;
    int s0 = p0 + (int)((long)len * j / 8);
    int s1 = p0 + (int)((long)len * (j + 1) / 8);
    for (int i = s0 + t; i < s1; i += 256)
        atomicAdd(&cnt[pairs[i] & (BSZ - 1)], 1);
    __syncthreads();
    int base = k << BSH;
    for (int i = t; i < BSZ; i += 256) {
        int c = cnt[i];
        if (c > 0 && base + i < N) atomicAdd(&degi[base + i], c);
    }
}

__global__ __launch_bounds__(256) void k_dinv(const int* __restrict__ degi,
                                              float* __restrict__ dinv) {
    int i = blockIdx.x * blockDim.x + threadIdx.x;
    if (i < N) dinv[i] = rsqrtf((float)degi[i] + 1.0f);   // +1 self loop
}

// ---------------- compute ----------------

// h1[i][j] = dinv[i] * sum_k x[i][k] * W1[k][j], fp16, rows padded to 64
__global__ __launch_bounds__(256, 2) void k_gemm1(const float* __restrict__ x,
                                                  const float* __restrict__ W1,
                                                  const float* __restrict__ dinv,
                                                  __half* __restrict__ h1) {
    __shared__ float xs[64][XS_LD];
    __shared__ float Ws[F_IN][WS_LD];
    const int t = threadIdx.x;
    const int row0 = blockIdx.x * 64;

    for (int i = t; i < F_IN * H; i += 256)
        Ws[i / H][i % H] = W1[i];
    for (int i = t; i < F_IN * (WS_LD - H); i += 256)
        Ws[i / (WS_LD - H)][H + i % (WS_LD - H)] = 0.0f;
    for (int i = t; i < 64 * (F_IN / 4); i += 256) {
        int r  = i >> 5;
        int c4 = i & 31;
        int gr = row0 + r;
        float4 v = make_float4(0.f, 0.f, 0.f, 0.f);
        if (gr < N) v = *(const float4*)(x + (long)gr * F_IN + c4 * 4);
        *(float4*)&xs[r][c4 * 4] = v;
    }
    __syncthreads();

    const int r  = t >> 2;
    const int g  = t & 3;
    const int j0 = g * 16;
    float acc[16];
    #pragma unroll
    for (int u = 0; u < 16; ++u) acc[u] = 0.0f;

    const float* xrow = &xs[r][0];
    #pragma unroll 4
    for (int k0 = 0; k0 < F_IN; k0 += 4) {
        float4 xv = *(const float4*)(xrow + k0);
        float xk[4] = {xv.x, xv.y, xv.z, xv.w};
        #pragma unroll
        for (int kk = 0; kk < 4; ++kk) {
            const float* wrow = &Ws[k0 + kk][j0];
            float4 wa = *(const float4*)(wrow);
            float4 wb = *(const float4*)(wrow + 4);
            float4 wc = *(const float4*)(wrow + 8);
            float4 wd = *(const float4*)(wrow + 12);
            float xr = xk[kk];
            acc[0]  += xr * wa.x; acc[1]  += xr * wa.y;
            acc[2]  += xr * wa.z; acc[3]  += xr * wa.w;
            acc[4]  += xr * wb.x; acc[5]  += xr * wb.y;
            acc[6]  += xr * wb.z; acc[7]  += xr * wb.w;
            acc[8]  += xr * wc.x; acc[9]  += xr * wc.y;
            acc[10] += xr * wc.z; acc[11] += xr * wc.w;
            acc[12] += xr * wd.x; acc[13] += xr * wd.y;
            acc[14] += xr * wd.z; acc[15] += xr * wd.w;
        }
    }

    int gr = row0 + r;
    if (gr >= N) return;
    float di = dinv[gr];
    __half* hrow = h1 + (long)gr * HP + j0;
    #pragma unroll
    for (int u = 0; u < 16; u += 2) {
        int j = j0 + u;
        if (j < H) {
            __half2 hv;
            hv.x = __float2half(di * acc[u]);
            hv.y = (j + 1 < H) ? __float2half(di * acc[u + 1]) : __half(0);
            *(__half2*)(hrow + u) = hv;
        }
    }
}

// layer-1 aggregation from pairs: block = 256-node sub-bucket; stream parent
// bucket's pairs, gather h1 rows, LDS-accumulate; finalize self+relu+W2 -> h2
__global__ __launch_bounds__(256) void k_agg1_pairs(const int* __restrict__ pairs,
                                                    const int* __restrict__ bptr,
                                                    const __half* __restrict__ h1,
                                                    const float* __restrict__ dinv,
                                                    const float* __restrict__ b1,
                                                    const float* __restrict__ W2,
                                                    float* __restrict__ h2) {
    __shared__ float acc[256][ACC_LD];   // 53.2 KB
    const int t = threadIdx.x, lane = t & 63, wid = t >> 6;
    const int k = blockIdx.x >> 3, j = blockIdx.x & 7;
    const int dlo = j * 256;
    const long nbase = (long)k * BSZ + dlo;

    for (int i = t; i < 256 * ACC_LD; i += 256) ((float*)acc)[i] = 0.0f;
    __syncthreads();

    const int p0 = bptr[k], p1 = bptr[k + 1];
    for (int i = p0 + t; i < p1; i += 256) {
        int pk = pairs[i];
        int dl = (pk & (BSZ - 1)) - dlo;
        if ((unsigned)dl < 256u) {
            const __half* row = h1 + (long)(pk >> BSH) * HP;
            short8v r0 = *(const short8v*)(row);
            short8v r1 = *(const short8v*)(row + 8);
            short8v r2 = *(const short8v*)(row + 16);
            short8v r3 = *(const short8v*)(row + 24);
            short8v r4 = *(const short8v*)(row + 32);
            short8v r5 = *(const short8v*)(row + 40);
            unsigned tb = *(const unsigned*)(row + 48);
            float* a = &acc[dl][0];
            #pragma unroll
            for (int v = 0; v < 8; ++v) {
                atomicAdd(a +  0 + v, h2f(r0[v]));
                atomicAdd(a +  8 + v, h2f(r1[v]));
                atomicAdd(a + 16 + v, h2f(r2[v]));
                atomicAdd(a + 24 + v, h2f(r3[v]));
                atomicAdd(a + 32 + v, h2f(r4[v]));
                atomicAdd(a + 40 + v, h2f(r5[v]));
            }
            atomicAdd(a + 48, h2f((short)(tb & 0xFFFF)));
            atomicAdd(a + 49, h2f((short)(tb >> 16)));
        }
    }
    __syncthreads();

    const bool act = lane < H;
    const float b1v = act ? b1[lane] : 0.0f;
    const float w20 = act ? W2[lane * 2 + 0] : 0.0f;
    const float w21 = act ? W2[lane * 2 + 1] : 0.0f;
    for (int nl = wid; nl < 256; nl += 4) {      // wave per node
        long node = nbase + nl;
        if (node >= N) continue;
        float di = dinv[node];
        float aval = act ? acc[nl][lane] + __half2float(h1[node * HP + lane]) : 0.0f;
        float v = fmaxf(di * aval + b1v, 0.0f);
        float p0v = v * w20, p1v = v * w21;
        #pragma unroll
        for (int o = 32; o > 0; o >>= 1) {
            p0v += __shfl_xor(p0v, o);
            p1v += __shfl_xor(p1v, o);
        }
        if (lane == 0) {
            h2[node * 2 + 0] = di * p0v;
            h2[node * 2 + 1] = di * p1v;
        }
    }
}

// layer-2 aggregation + log_softmax from pairs
__global__ __launch_bounds__(256) void k_agg2_pairs(const int* __restrict__ pairs,
                                                    const int* __restrict__ bptr,
                                                    const float* __restrict__ h2,
                                                    const float* __restrict__ dinv,
                                                    const float* __restrict__ b2,
                                                    float* __restrict__ out) {
    __shared__ float accA[256][2];
    const int t = threadIdx.x;
    const int k = blockIdx.x >> 3, j = blockIdx.x & 7;
    const int dlo = j * 256;
    const long nbase = (long)k * BSZ + dlo;

    for (int i = t; i < 512; i += 256) ((float*)accA)[i] = 0.0f;
    __syncthreads();

    const int p0 = bptr[k], p1 = bptr[k + 1];
    for (int i = p0 + t; i < p1; i += 256) {
        int pk = pairs[i];
        int dl = (pk & (BSZ - 1)) - dlo;
        if ((unsigned)dl < 256u) {
            const float* hp = h2 + (long)(pk >> BSH) * 2;
            atomicAdd(&accA[dl][0], hp[0]);
            atomicAdd(&accA[dl][1], hp[1]);
        }
    }
    __syncthreads();

    long node = nbase + t;
    if (node < N) {
        float di = dinv[node];
        float a0 = di * (accA[t][0] + h2[node * 2 + 0]) + b2[0];
        float a1 = di * (accA[t][1] + h2[node * 2 + 1]) + b2[1];
        float m = fmaxf(a0, a1);
        float lse = m + logf(expf(a0 - m) + expf(a1 - m));
        out[node * 2 + 0] = a0 - lse;
        out[node * 2 + 1] = a1 - lse;
    }
}

extern "C" void kernel_launch(void* const* d_in, const int* in_sizes, int n_in,
                              void* d_out, int out_size, void* d_ws, size_t ws_size,
                              hipStream_t stream) {
    const float* x  = (const float*)d_in[0];
    const int*   ei = (const int*)d_in[1];   // [2][E]: row0 src, row1 dst
    const float* W1 = (const float*)d_in[2];
    const float* b1 = (const float*)d_in[3];
    const float* W2 = (const float*)d_in[4];
    const float* b2 = (const float*)d_in[5];
    float* out = (float*)d_out;

    const int* src = ei;
    const int* dst = ei + E;

    // ws layout
    int*    degi = (int*)d_ws;               // N
    int*    bcnt = degi + N;                 // 64
    int*    bptr = bcnt + 64;                // 64 (needs 50)
    int*    gcur = bptr + 64;                // 64
    float*  dinv = (float*)(gcur + 64);      // N
    int*    pairs = (int*)(dinv + N);        // E
    __half* h1   = (__half*)(pairs + E);     // N*64 halves (12.8 MB)
    float*  h2   = (float*)(h1 + (long)N * HP);  // N*2  (~27 MB total)

    k_zero<<<(N + 255) / 256, 256, 0, stream>>>(degi, bcnt);
    k_coarse<<<PART_NBLK, 256, 0, stream>>>(dst, bcnt);
    k_scan49<<<1, 64, 0, stream>>>(bcnt, bptr, gcur);
    k_part<<<PART_NBLK, 256, 0, stream>>>(src, dst, gcur, pairs);
    k_bdeg<<<NBUCK * 8, 256, 0, stream>>>(pairs, bptr, degi);
    k_dinv<<<(N + 255) / 256, 256, 0, stream>>>(degi, dinv);
    k_gemm1<<<(N + 63) / 64, 256, 0, stream>>>(x, W1, dinv, h1);
    k_agg1_pairs<<<NBUCK * 8, 256, 0, stream>>>(pairs, bptr, h1, dinv, b1, W2, h2);
    k_agg2_pairs<<<NBUCK * 8, 256, 0, stream>>>(pairs, bptr, h2, dinv, b2, out);
}